// Round 4
// baseline (816.583 us; speedup 1.0000x reference)
//
#include <hip/hip_runtime.h>
#include <hip/hip_fp16.h>

#define HEADS 8
#define F_IN 256
#define OUT 64
#define NOUT 512   // HEADS*OUT

typedef __attribute__((ext_vector_type(8))) _Float16 f16x8;
typedef __attribute__((ext_vector_type(2))) _Float16 f16x2;
typedef __attribute__((ext_vector_type(4))) float f32x4;

__device__ __forceinline__ short f2h(float f) {
  _Float16 h = (_Float16)f;
  return *(short*)&h;
}
__device__ __forceinline__ f16x2 u2h2(unsigned u) {
  union { unsigned u; f16x2 h; } x; x.u = u; return x.h;
}
__device__ __forceinline__ float h2f(unsigned short b) {
  _Float16 h = *(_Float16*)&b; return (float)h;
}
__device__ __forceinline__ unsigned pkmul(unsigned a, f16x2 w) {
  f16x2 r = u2h2(a) * w; return *(unsigned*)&r;
}

// ---------------------------------------------------------------------------
// Convert f32 -> f16 bits, 8 elems/thread
// ---------------------------------------------------------------------------
__global__ __launch_bounds__(256) void conv_kernel(
    const float* __restrict__ src, short* __restrict__ dst, int n8)
{
  int i = blockIdx.x * 256 + threadIdx.x;
  if (i >= n8) return;
  const float4 a = *(const float4*)(src + (size_t)i * 8);
  const float4 b = *(const float4*)(src + (size_t)i * 8 + 4);
  short r[8] = { f2h(a.x), f2h(a.y), f2h(a.z), f2h(a.w),
                 f2h(b.x), f2h(b.y), f2h(b.z), f2h(b.w) };
  *(uint4*)(dst + (size_t)i * 8) = *(uint4*)r;
}

// ---------------------------------------------------------------------------
// MFMA GEMM (f16): writes u in SLICE-MAJOR layout u[(h*2+p)][n][32]
// (p = output-half). Each 3.2MB slice fits one XCD's 4MB L2 for agg.
// Fused epilogue: Ar[h][n] (Al cancels in row-softmax; never computed).
// ---------------------------------------------------------------------------
__global__ __launch_bounds__(256) void gemm_mfma(
    const short* __restrict__ xh, const short* __restrict__ W2,
    const float* __restrict__ As, const float* __restrict__ Asb,
    short* __restrict__ u, float* __restrict__ Ar, int N)
{
  __shared__ __align__(16) short as[128][72];  // 144B row stride: 2-way bank alias (free)
  __shared__ __align__(16) short bs[64][72];
  const int tid = threadIdx.x;
  const int h  = blockIdx.x;            // col tile == head
  const int n0 = blockIdx.y * 128;
  const int lane = tid & 63, wave = tid >> 6;
  const int lcol = lane & 15, quad = lane >> 4;
  const int m0 = wave * 32;
  const short* Wh = W2 + h * OUT * F_IN;

  f32x4 acc[2][4] = {};

  for (int k0 = 0; k0 < F_IN; k0 += 64) {
    __syncthreads();
    #pragma unroll
    for (int p = 0; p < 4; ++p) {
      int id = tid + 256 * p;
      int r = id >> 3, s = id & 7;
      int n = n0 + r;
      uint4 v = make_uint4(0, 0, 0, 0);
      if (n < N) v = *(const uint4*)(xh + (size_t)n * F_IN + k0 + s * 8);
      *(uint4*)&as[r][s * 8] = v;
    }
    #pragma unroll
    for (int p = 0; p < 2; ++p) {
      int id = tid + 256 * p;
      int r = id >> 3, s = id & 7;
      uint4 v = *(const uint4*)(Wh + r * F_IN + k0 + s * 8);
      *(uint4*)&bs[r][s * 8] = v;
    }
    __syncthreads();
    #pragma unroll
    for (int ks = 0; ks < 2; ++ks) {
      f16x8 af[2], bf[4];
      #pragma unroll
      for (int i = 0; i < 2; ++i)
        af[i] = *(const f16x8*)&as[m0 + i * 16 + lcol][ks * 32 + quad * 8];
      #pragma unroll
      for (int j = 0; j < 4; ++j)
        bf[j] = *(const f16x8*)&bs[j * 16 + lcol][ks * 32 + quad * 8];
      #pragma unroll
      for (int i = 0; i < 2; ++i)
        #pragma unroll
        for (int j = 0; j < 4; ++j)
          acc[i][j] = __builtin_amdgcn_mfma_f32_16x16x32_f16(
              af[i], bf[j], acc[i][j], 0, 0, 0);
    }
  }

  // epilogue: u (f16, slice-major) + fused Ar
  float arw_l[4];
  #pragma unroll
  for (int j = 0; j < 4; ++j) arw_l[j] = As[h * 2 * OUT + OUT + j * 16 + lcol];
  const float arb = Asb[h * 2 + 1];
  #pragma unroll
  for (int i = 0; i < 2; ++i) {
    #pragma unroll
    for (int reg = 0; reg < 4; ++reg) {
      int n = n0 + m0 + i * 16 + quad * 4 + reg;
      float pr = 0.f;
      #pragma unroll
      for (int j = 0; j < 4; ++j) pr = fmaf(acc[i][j][reg], arw_l[j], pr);
      #pragma unroll
      for (int off = 1; off < 16; off <<= 1) pr += __shfl_xor(pr, off);
      if (n < N) {
        if (lcol == 0) Ar[(size_t)h * N + n] = pr + arb;
        #pragma unroll
        for (int j = 0; j < 4; ++j) {
          const int hp = h * 2 + (j >> 1);
          u[((size_t)hp * N + n) * 32 + (j & 1) * 16 + lcol] =
              f2h(acc[i][j][reg]);
        }
      }
    }
  }
}

// ---------------------------------------------------------------------------
// CSR build: histogram -> 3-phase multi-block scan -> counting-sort scatter
// ---------------------------------------------------------------------------
#define SB 128

__global__ void hist_kernel(const int* __restrict__ row, int* __restrict__ deg, int E)
{
  int e = blockIdx.x * 256 + threadIdx.x;
  if (e < E) atomicAdd(&deg[row[e]], 1);
}

__global__ __launch_bounds__(256) void scan1_kernel(
    const int* __restrict__ deg, int* __restrict__ bsum, int N)
{
  const int b = blockIdx.x;
  const int C = (N + SB - 1) / SB;
  const int base = b * C;
  int s = 0;
  for (int i = threadIdx.x; i < C; i += 256) {
    int idx = base + i;
    if (idx < N) s += deg[idx];
  }
  #pragma unroll
  for (int off = 32; off >= 1; off >>= 1) s += __shfl_xor(s, off);
  __shared__ int sm[4];
  if ((threadIdx.x & 63) == 0) sm[threadIdx.x >> 6] = s;
  __syncthreads();
  if (threadIdx.x == 0) bsum[b] = sm[0] + sm[1] + sm[2] + sm[3];
}

__global__ __launch_bounds__(SB) void scan2_kernel(
    const int* __restrict__ bsum, int* __restrict__ bofs, int* __restrict__ total)
{
  __shared__ int sd[SB];
  const int t = threadIdx.x;
  int v = bsum[t];
  sd[t] = v;
  __syncthreads();
  for (int off = 1; off < SB; off <<= 1) {
    int u = (t >= off) ? sd[t - off] : 0;
    __syncthreads();
    sd[t] += u;
    __syncthreads();
  }
  bofs[t] = sd[t] - v;
  if (t == SB - 1) total[0] = sd[t];
}

__global__ __launch_bounds__(256) void scan3_kernel(
    const int* __restrict__ deg, const int* __restrict__ bofs,
    int* __restrict__ row_ptr, int N)
{
  const int b = blockIdx.x;
  const int C = (N + SB - 1) / SB;
  const int CH = (C + 255) / 256;
  const int base = b * C;
  const int lim = min(base + C, N);
  const int start = base + threadIdx.x * CH;
  int vals[4];
  int s = 0;
  for (int i = 0; i < CH; ++i) {
    int idx = start + i;
    vals[i] = (idx < lim) ? deg[idx] : 0;
    s += vals[i];
  }
  __shared__ int sd[256];
  sd[threadIdx.x] = s;
  __syncthreads();
  for (int off = 1; off < 256; off <<= 1) {
    int u = (threadIdx.x >= off) ? sd[threadIdx.x - off] : 0;
    __syncthreads();
    sd[threadIdx.x] += u;
    __syncthreads();
  }
  int excl = sd[threadIdx.x] - s + bofs[b];
  for (int i = 0; i < CH; ++i) {
    int idx = start + i;
    if (idx < lim) { row_ptr[idx] = excl; excl += vals[i]; }
  }
}

__global__ void scatter_kernel(const int* __restrict__ row, const int* __restrict__ col,
                               const int* __restrict__ row_ptr, int* __restrict__ cursor,
                               int* __restrict__ col_sorted, int E)
{
  int e = blockIdx.x * 256 + threadIdx.x;
  if (e < E) {
    int r = row[e];
    int pos = atomicAdd(&cursor[r], 1);
    col_sorted[row_ptr[r] + pos] = col[e];
  }
}

// ---------------------------------------------------------------------------
// Per-head global max of Ar, then Wh16[n][8] = f16(exp(Ar-mh)).
// ---------------------------------------------------------------------------
__global__ __launch_bounds__(256) void maxred_kernel(
    const float* __restrict__ Ar, float* __restrict__ m, int N)
{
  const int h = blockIdx.x;
  const float* a = Ar + (size_t)h * N;
  float mm = -1e30f;
  for (int i = threadIdx.x; i < N; i += 256) mm = fmaxf(mm, a[i]);
  #pragma unroll
  for (int off = 32; off >= 1; off >>= 1) mm = fmaxf(mm, __shfl_xor(mm, off));
  __shared__ float sm[4];
  if ((threadIdx.x & 63) == 0) sm[threadIdx.x >> 6] = mm;
  __syncthreads();
  if (threadIdx.x == 0)
    m[h] = fmaxf(fmaxf(sm[0], sm[1]), fmaxf(sm[2], sm[3]));
}

__global__ __launch_bounds__(256) void expw_kernel(
    const float* __restrict__ Ar, const float* __restrict__ m,
    unsigned short* __restrict__ Wh16, int N)
{
  const int i = blockIdx.x * 256 + threadIdx.x;
  if (i >= N * HEADS) return;
  const int n = i >> 3, h = i & 7;
  float w = __expf(Ar[(size_t)h * N + n] - m[h]);
  Wh16[i] = (unsigned short)f2h(w);
}

// ---------------------------------------------------------------------------
// Premultiply u *= w[h][n] in place (u slice-major [hp][n][32]).
// Streaming, fully coalesced; grid.y = slice (16).
// ---------------------------------------------------------------------------
__global__ __launch_bounds__(256) void scale_kernel(
    unsigned short* __restrict__ u, const unsigned short* __restrict__ Wh16, int N)
{
  const int cid = blockIdx.x * 256 + threadIdx.x;   // 16B chunk within slice
  if (cid >= N * 4) return;
  const int slice = blockIdx.y;
  const int n = cid >> 2;
  const int h = slice >> 1;
  const unsigned short wb = Wh16[n * 8 + h];
  const unsigned ww = (unsigned)wb * 0x10001u;
  const f16x2 w2 = u2h2(ww);
  unsigned short* pbase = u + ((size_t)slice * N * 4 + cid) * 8;
  uint4 v = *(const uint4*)pbase;
  v.x = pkmul(v.x, w2); v.y = pkmul(v.y, w2);
  v.z = pkmul(v.z, w2); v.w = pkmul(v.w, w2);
  *(uint4*)pbase = v;
}

// ---------------------------------------------------------------------------
// Denominator SpMV: swb[n][8] = sum_{j in N(n)} w[.][j]. Wh16 is 800KB ->
// L2-resident on every XCD; lane-per-edge, f32 accumulate, full-wave reduce.
// ---------------------------------------------------------------------------
__global__ __launch_bounds__(256) void sw_kernel(
    const int* __restrict__ row_ptr, const int* __restrict__ col_sorted,
    const unsigned short* __restrict__ Wh16, float* __restrict__ swb, int N)
{
  const int lane = threadIdx.x & 63;
  const int wave = threadIdx.x >> 6;
  const int row = blockIdx.x * 4 + wave;
  if (row >= N) return;
  const int start = row_ptr[row], end = row_ptr[row + 1];
  float a[8];
  #pragma unroll
  for (int i = 0; i < 8; ++i) a[i] = 0.f;
  for (int e = start + lane; e < end; e += 64) {
    int c = col_sorted[e];
    uint4 v = *(const uint4*)(Wh16 + (size_t)c * 8);
    a[0] += h2f(v.x & 0xffff); a[1] += h2f(v.x >> 16);
    a[2] += h2f(v.y & 0xffff); a[3] += h2f(v.y >> 16);
    a[4] += h2f(v.z & 0xffff); a[5] += h2f(v.z >> 16);
    a[6] += h2f(v.w & 0xffff); a[7] += h2f(v.w >> 16);
  }
  #pragma unroll
  for (int off = 1; off <= 32; off <<= 1) {
    #pragma unroll
    for (int i = 0; i < 8; ++i) a[i] += __shfl_xor(a[i], off);
  }
  if (lane == 0) {
    float* sp = swb + (size_t)row * 8;
    *(float4*)sp       = make_float4(a[0], a[1], a[2], a[3]);
    *((float4*)sp + 1) = make_float4(a[4], a[5], a[6], a[7]);
  }
}

// ---------------------------------------------------------------------------
// Aggregation half-kernel: out[:, :, p*32:(p+1)*32] for all heads.
// One wave per (row, head); head = blockIdx.x % 8 pins each head to one XCD
// (round-robin dispatch) -> per-XCD gather working set = one 3.2MB u slice,
// fully L2-resident. col_sorted loaded NON-TEMPORALLY so the stream can't
// evict the slice. Lane = (g=lane>>2 in [0,16), sub=lane&3): 32 edges/iter,
// 2 edges/lane paired via v_perm + v_dot2_f32_f16. Masked tail iteration.
// ---------------------------------------------------------------------------
#define AGG_BODY(MASKED)                                                      \
  {                                                                           \
    int ea = e + 2 * g, eb = ea + 1;                                          \
    int ia = (MASKED) ? min(ea, last) : ea;                                   \
    int ib = (MASKED) ? min(eb, last) : eb;                                   \
    int ca = __builtin_nontemporal_load(col_sorted + ia);                     \
    int cb = __builtin_nontemporal_load(col_sorted + ib);                     \
    uint4 va = *(const uint4*)(ub + (size_t)ca * 32);                         \
    uint4 vb = *(const uint4*)(ub + (size_t)cb * 32);                         \
    unsigned aw[4] = { va.x, va.y, va.z, va.w };                              \
    unsigned bw[4] = { vb.x, vb.y, vb.z, vb.w };                              \
    if (MASKED) {                                                             \
      unsigned ma = (ea < end) ? 0xffffffffu : 0u;                            \
      unsigned mb = (eb < end) ? 0xffffffffu : 0u;                            \
      _Pragma("unroll")                                                       \
      for (int q2 = 0; q2 < 4; ++q2) { aw[q2] &= ma; bw[q2] &= mb; }          \
    }                                                                         \
    _Pragma("unroll")                                                         \
    for (int q = 0; q < 4; ++q) {                                             \
      unsigned plo = __builtin_amdgcn_perm(bw[q], aw[q], 0x05040100u);        \
      unsigned phi = __builtin_amdgcn_perm(bw[q], aw[q], 0x07060302u);        \
      acc[2*q]   = __builtin_amdgcn_fdot2(u2h2(plo), ones, acc[2*q],   false);\
      acc[2*q+1] = __builtin_amdgcn_fdot2(u2h2(phi), ones, acc[2*q+1], false);\
    }                                                                         \
  }

__global__ __launch_bounds__(256) void agg_kernel(
    const int* __restrict__ row_ptr, const int* __restrict__ col_sorted,
    const unsigned short* __restrict__ u, const float* __restrict__ swb,
    const float* __restrict__ Wb, float* __restrict__ out, int N, int p)
{
  const int lane = threadIdx.x & 63;
  const int wave = threadIdx.x >> 6;
  const int head = blockIdx.x & 7;              // XCD pin (round-robin %8)
  const int row  = (blockIdx.x >> 3) * 4 + wave;
  if (row >= N) return;
  const int g = lane >> 2, sub = lane & 3;
  const unsigned short* ub =
      u + ((size_t)(head * 2 + p) * N) * 32 + sub * 8;
  const int start = row_ptr[row], end = row_ptr[row + 1];
  const int last = end - 1;

  float acc[8];
  #pragma unroll
  for (int i = 0; i < 8; ++i) acc[i] = 0.f;
  const f16x2 ones = {(_Float16)1.0f, (_Float16)1.0f};

  int e = start;
  for (; e + 32 <= end; e += 32) AGG_BODY(false)
  if (e < end) AGG_BODY(true)

  // reduce over g (lane stride 4)
  #pragma unroll
  for (int off = 4; off <= 32; off <<= 1) {
    #pragma unroll
    for (int i = 0; i < 8; ++i) acc[i] += __shfl_xor(acc[i], off);
  }

  if (g == 0) {
    const float sw = swb[(size_t)row * 8 + head];
    const float inv = (sw > 0.f) ? 1.f / sw : 0.f;
    const int bidx = head * OUT + p * 32 + sub * 8;
    const float4 b0 = *(const float4*)(Wb + bidx);
    const float4 b1 = *(const float4*)(Wb + bidx + 4);
    const float bb[8] = { b0.x, b0.y, b0.z, b0.w, b1.x, b1.y, b1.z, b1.w };
    float r[8];
    #pragma unroll
    for (int i = 0; i < 8; ++i) {
      float y = acc[i] * inv + bb[i];
      r[i] = (y > 0.f) ? y : (__expf(y) - 1.f);
    }
    float* op = out + (size_t)row * NOUT + bidx;
    *(float4*)op       = make_float4(r[0], r[1], r[2], r[3]);
    *((float4*)op + 1) = make_float4(r[4], r[5], r[6], r[7]);
  }
}

// ---------------------------------------------------------------------------
extern "C" void kernel_launch(void* const* d_in, const int* in_sizes, int n_in,
                              void* d_out, int out_size, void* d_ws, size_t ws_size,
                              hipStream_t stream)
{
  const float* x    = (const float*)d_in[0];
  const int*   erow = (const int*)d_in[1];
  const int*   ecol = (const int*)d_in[2];
  const float* Ws   = (const float*)d_in[3];
  const float* Wb   = (const float*)d_in[4];
  const float* As   = (const float*)d_in[5];
  const float* Asb  = (const float*)d_in[6];
  float* out = (float*)d_out;
  const int N = in_sizes[0] / F_IN;
  const int E = in_sizes[1];

  char* p = (char*)d_ws;
  short* u       = (short*)p; p += (size_t)HEADS * N * OUT * sizeof(short);
  short* xh      = (short*)p; p += (size_t)N * F_IN * sizeof(short);
  short* W2      = (short*)p; p += (size_t)NOUT * F_IN * sizeof(short);
  float* Ar      = (float*)p; p += (size_t)HEADS * N * sizeof(float);
  unsigned short* Wh16 = (unsigned short*)p; p += (size_t)N * HEADS * sizeof(short);
  float* swb     = (float*)p; p += (size_t)N * HEADS * sizeof(float);
  float* mbuf    = (float*)p; p += 64 * sizeof(float);
  int* row_ptr   = (int*)p;   p += (size_t)(N + 1) * sizeof(int);
  int* deg       = (int*)p;   p += (size_t)N * sizeof(int);   // deg+cursor adjacent:
  int* cursor    = (int*)p;   p += (size_t)N * sizeof(int);   // one memset covers both
  int* bsum      = (int*)p;   p += SB * sizeof(int);
  int* bofs      = (int*)p;   p += SB * sizeof(int);
  int* col_sorted= (int*)p;   p += (size_t)E * sizeof(int);

  (void)hipMemsetAsync(deg, 0, (size_t)2 * N * sizeof(int), stream);

  // CSR build
  hist_kernel<<<dim3((E + 255) / 256), dim3(256), 0, stream>>>(erow, deg, E);
  scan1_kernel<<<dim3(SB), dim3(256), 0, stream>>>(deg, bsum, N);
  scan2_kernel<<<dim3(1), dim3(SB), 0, stream>>>(bsum, bofs, row_ptr + N);
  scan3_kernel<<<dim3(SB), dim3(256), 0, stream>>>(deg, bofs, row_ptr, N);
  scatter_kernel<<<dim3((E + 255) / 256), dim3(256), 0, stream>>>(
      erow, ecol, row_ptr, cursor, col_sorted, E);

  // f16 conversions
  conv_kernel<<<dim3((N * F_IN / 8 + 255) / 256), dim3(256), 0, stream>>>(
      x, xh, N * F_IN / 8);
  conv_kernel<<<dim3((NOUT * F_IN / 8 + 255) / 256), dim3(256), 0, stream>>>(
      Ws, W2, NOUT * F_IN / 8);

  // MFMA GEMM + fused Ar (slice-major u output, unscaled)
  dim3 gg(HEADS, (N + 127) / 128);
  gemm_mfma<<<gg, dim3(256), 0, stream>>>(xh, W2, As, Asb, u, Ar, N);

  maxred_kernel<<<dim3(HEADS), dim3(256), 0, stream>>>(Ar, mbuf, N);
  expw_kernel<<<dim3((N * HEADS + 255) / 256), dim3(256), 0, stream>>>(
      Ar, mbuf, Wh16, N);

  // u *= w  (in place, streaming)
  scale_kernel<<<dim3((N * 4 + 255) / 256, 16), dim3(256), 0, stream>>>(
      (unsigned short*)u, Wh16, N);

  // denominators
  sw_kernel<<<dim3((N + 3) / 4), dim3(256), 0, stream>>>(
      row_ptr, col_sorted, Wh16, swb, N);

  // aggregation: two sequential half-kernels, head->XCD pinned
  const int nblk = 8 * ((N + 3) / 4);
  agg_kernel<<<dim3(nblk), dim3(256), 0, stream>>>(
      row_ptr, col_sorted, (const unsigned short*)u, swb, Wb, out, N, 0);
  agg_kernel<<<dim3(nblk), dim3(256), 0, stream>>>(
      row_ptr, col_sorted, (const unsigned short*)u, swb, Wb, out, N, 1);
}